// Round 8
// baseline (762.375 us; speedup 1.0000x reference)
//
#include <hip/hip_runtime.h>
#include <math.h>

#define N_ROWS 65536
#define DDIM   256
#define KCODES 1024
#define MARGIN 2.2e-4f    // >= 1.22e-4 (np f32-grid) + 2*4.4e-5 (C-S worst-case s~ err)
#define PAIR_CAP 2048
#define ESCALE 32768.0f   // 2^15: keeps f16 codebook out of subnormals
#define FOLDC  (-6.103515625e-05f)   // -2 * 2^-15 exact

typedef __attribute__((ext_vector_type(8))) _Float16 f16x8;  // 4 VGPR
typedef __attribute__((ext_vector_type(4))) float f32x4;

// ws layout (bytes):
//      0 : C32[1024]   f32  (np-pairwise codebook norms)
//   4096 : m1arr[65536] f32
// 266240 : idx_arr[65536] i32
// 528384 : list[65536]    i32
// 790528 : count i32 (+4 pad)
// 790536 : partials[2048] f64
// 807936 : cbfrag[512 KB] f16 codebook*2^15 in MFMA A-frag order
// slice partials (4 MB) live in d_out's quantized region (overwritten by kout later)

// ---------- numpy-pairwise f32 row-norm emulation (n=256), codebook only ----------
__global__ void krownorm(const float* __restrict__ x, float* __restrict__ out) {
    const int row = blockIdx.x * 16 + (threadIdx.x >> 4);
    const int l16 = threadIdx.x & 15;
    const int half = l16 >> 3, j = l16 & 7;
    const float* p = x + (size_t)row * DDIM + half * 128 + j;
    float t0 = p[0];
    float r = __fmul_rn(t0, t0);
    #pragma unroll
    for (int i = 1; i < 16; ++i) {
        const float t = p[i * 8];
        r = __fadd_rn(r, __fmul_rn(t, t));
    }
    float o = __fadd_rn(r, __shfl_xor(r, 1, 64));
    o = __fadd_rn(o, __shfl_xor(o, 2, 64));
    o = __fadd_rn(o, __shfl_xor(o, 4, 64));
    o = __fadd_rn(o, __shfl_xor(o, 8, 64));
    if (l16 == 0) out[row] = o;
}

// ---------- codebook*2^15 -> f16 A-fragments ----------
// elem j of (ct,c,g,code): cbfrag[ct*4096 + (c*4+g)*128 + code*8 + j]
__global__ void kprep(const float* __restrict__ cb, _Float16* __restrict__ frag) {
    const int u = blockIdx.x * 256 + threadIdx.x;     // 32768 units
    const int code = u & 15, g = (u >> 4) & 3, c = (u >> 6) & 7, ct = u >> 9;
    const float* src = cb + (size_t)(ct * 16 + code) * DDIM + c * 32 + g * 8;
    const float4 f0 = *reinterpret_cast<const float4*>(src);
    const float4 f1 = *reinterpret_cast<const float4*>(src + 4);
    float v[8] = {f0.x, f0.y, f0.z, f0.w, f1.x, f1.y, f1.z, f1.w};
    f16x8 H;
    #pragma unroll
    for (int j = 0; j < 8; ++j) H[j] = (_Float16)(v[j] * ESCALE);
    *reinterpret_cast<f16x8*>(frag + (size_t)ct * 4096 + (c * 4 + g) * 128 + code * 8) = H;
}

// ---- phase A: LDS-resident code-slice (256 codes, 128 KB), barrier-free main loop ----
// grid 256 = 64 rowgroups x 4 slices; 512 thr (8 waves). Block loads its slice into
// dynamic LDS once; each wave: 4 chunks x (32 rows R=2) x 16 code-tiles of
// {8 ds_read_b128 + 16 MFMA + sort-network fold}. Emits per-row (m1,m2,i1) partials.
__global__ __launch_bounds__(512, 2) void kdist_slice(const float* __restrict__ z,
        const _Float16* __restrict__ cbfrag, const float* __restrict__ C32,
        float4* __restrict__ part) {
    extern __shared__ __align__(16) char smem[];
    _Float16* fragS = (_Float16*)smem;            // 131072 B
    float*    c32sl = (float*)(smem + 131072);    // 1024 B

    const int tid = threadIdx.x;
    const int slice = blockIdx.x & 3;
    const int rowgrp = blockIdx.x >> 2;
    const int w = tid >> 6, l = tid & 63;
    const int lg = l >> 4, lc = l & 15;

    // one-time slice load (256 B/thread, coalesced)
    {
        const uint4* src = (const uint4*)(cbfrag + (size_t)slice * 65536);
        uint4* dst = (uint4*)fragS;
        #pragma unroll
        for (int i = 0; i < 16; ++i)
            dst[tid + i * 512] = src[tid + i * 512];
    }
    if (tid < 256) c32sl[tid] = C32[slice * 256 + tid];
    __syncthreads();     // only barrier; LDS is read-only below

    for (int j = 0; j < 4; ++j) {
        const int rbase = rowgrp * 1024 + w * 128 + j * 32;

        // z B-frags for 2 row-tiles, direct from global (f16, unscaled)
        f16x8 zh[2][8];
        #pragma unroll
        for (int t = 0; t < 2; ++t) {
            const int row = rbase + t * 16 + lc;
            #pragma unroll
            for (int c = 0; c < 8; ++c) {
                const float* p = z + (size_t)row * DDIM + c * 32 + lg * 8;
                const float4 f0 = *reinterpret_cast<const float4*>(p);
                const float4 f1 = *reinterpret_cast<const float4*>(p + 4);
                float v[8] = {f0.x, f0.y, f0.z, f0.w, f1.x, f1.y, f1.z, f1.w};
                f16x8 H;
                #pragma unroll
                for (int q = 0; q < 8; ++q) H[q] = (_Float16)v[q];
                zh[t][c] = H;
            }
        }

        float m1a = __builtin_inff(), m2a = __builtin_inff(); int i1a = 0;
        float m1b = __builtin_inff(), m2b = __builtin_inff(); int i1b = 0;

        for (int ct = 0; ct < 16; ++ct) {
            f32x4 acc0 = {0.f, 0.f, 0.f, 0.f}, acc1 = {0.f, 0.f, 0.f, 0.f};
            #pragma unroll
            for (int c = 0; c < 8; ++c) {
                const f16x8 A = *reinterpret_cast<const f16x8*>(
                    &fragS[ct * 4096 + (c * 4 + lg) * 128 + lc * 8]);
                acc0 = __builtin_amdgcn_mfma_f32_16x16x32_f16(A, zh[0][c], acc0, 0, 0, 0);
                acc1 = __builtin_amdgcn_mfma_f32_16x16x32_f16(A, zh[1][c], acc1, 0, 0, 0);
            }
            const float4 Cc = *reinterpret_cast<const float4*>(&c32sl[ct * 16 + lg * 4]);
            const int base = slice * 256 + ct * 16 + lg * 4;
            {   // tile top-2 fold, track a (same expression as kcand -> bitwise identical)
                const float s0 = fmaf(FOLDC, acc0[0], Cc.x);
                const float s1 = fmaf(FOLDC, acc0[1], Cc.y);
                const float s2 = fmaf(FOLDC, acc0[2], Cc.z);
                const float s3 = fmaf(FOLDC, acc0[3], Cc.w);
                const float lo01 = fminf(s0, s1), hi01 = fmaxf(s0, s1);
                const float lo23 = fminf(s2, s3), hi23 = fmaxf(s2, s3);
                const float a1 = fminf(lo01, lo23);
                const float a2 = fminf(fmaxf(lo01, lo23), fminf(hi01, hi23));
                const int it = (s0 == a1) ? base : (s1 == a1) ? base + 1
                             : (s2 == a1) ? base + 2 : base + 3;
                if (a1 < m1a) { m2a = fminf(m1a, a2); m1a = a1; i1a = it; }
                else          { m2a = fminf(m2a, a1); }
            }
            {   // track b
                const float s0 = fmaf(FOLDC, acc1[0], Cc.x);
                const float s1 = fmaf(FOLDC, acc1[1], Cc.y);
                const float s2 = fmaf(FOLDC, acc1[2], Cc.z);
                const float s3 = fmaf(FOLDC, acc1[3], Cc.w);
                const float lo01 = fminf(s0, s1), hi01 = fmaxf(s0, s1);
                const float lo23 = fminf(s2, s3), hi23 = fmaxf(s2, s3);
                const float a1 = fminf(lo01, lo23);
                const float a2 = fminf(fmaxf(lo01, lo23), fminf(hi01, hi23));
                const int it = (s0 == a1) ? base : (s1 == a1) ? base + 1
                             : (s2 == a1) ? base + 2 : base + 3;
                if (a1 < m1b) { m2b = fminf(m1b, a2); m1b = a1; i1b = it; }
                else          { m2b = fminf(m2b, a1); }
            }
        }

        // merge the 4 lane-groups (lanes l, l^16, l^32, l^48 share a z-row)
        #pragma unroll
        for (int off = 16; off < 64; off <<= 1) {
            float om1 = __shfl_xor(m1a, off, 64);
            float om2 = __shfl_xor(m2a, off, 64);
            int   oi  = __shfl_xor(i1a, off, 64);
            if (om1 < m1a) { m2a = fminf(m1a, om2); m1a = om1; i1a = oi; }
            else { m2a = fminf(m2a, om1); if (om1 == m1a) i1a = min(i1a, oi); }
            om1 = __shfl_xor(m1b, off, 64);
            om2 = __shfl_xor(m2b, off, 64);
            oi  = __shfl_xor(i1b, off, 64);
            if (om1 < m1b) { m2b = fminf(m1b, om2); m1b = om1; i1b = oi; }
            else { m2b = fminf(m2b, om1); if (om1 == m1b) i1b = min(i1b, oi); }
        }
        if (lg == 0) {
            float4 pa, pb;
            pa.x = m1a; pa.y = m2a; pa.z = __int_as_float(i1a); pa.w = 0.f;
            pb.x = m1b; pb.y = m2b; pb.z = __int_as_float(i1b); pb.w = 0.f;
            part[(size_t)slice * 65536 + rbase + lc]      = pa;
            part[(size_t)slice * 65536 + rbase + 16 + lc] = pb;
        }
    }
}

// ---------- merge 4 slice-partials per row -> idx, m1, flag list ----------
__global__ void kmerge(const float4* __restrict__ part, int* __restrict__ idx_arr,
                       float* __restrict__ m1arr, int* __restrict__ list,
                       int* __restrict__ count) {
    const int row = blockIdx.x * 256 + threadIdx.x;
    float m1 = __builtin_inff(), m2 = __builtin_inff(); int i1 = 0x7fffffff;
    #pragma unroll
    for (int s = 0; s < 4; ++s) {
        const float4 p = part[(size_t)s * 65536 + row];
        const float a1 = p.x, a2 = p.y;
        const int   ai = __float_as_int(p.z);
        if (a1 < m1) { m2 = fminf(m1, a2); m1 = a1; i1 = ai; }
        else { if (a1 == m1) i1 = min(i1, ai); m2 = fminf(m2, a1); }
    }
    idx_arr[row] = i1; m1arr[row] = m1;
    if (m2 - m1 < MARGIN) { const int p = atomicAdd(count, 1); list[p] = row; }
}

// -------- phase B: batched candidate emission (bitwise-identical s~) + exact refine --------
__global__ __launch_bounds__(256, 4) void kcand(const float* __restrict__ z,
        const float* __restrict__ cb, const _Float16* __restrict__ cbfrag,
        const float* __restrict__ C32, const float* __restrict__ m1arr,
        const int* __restrict__ list, const int* __restrict__ count,
        int* __restrict__ idx_arr) {
    __shared__ float c32s[1024];
    __shared__ int rowids[64];
    __shared__ float m1s[64];
    __shared__ float arow[64];
    __shared__ unsigned long long packed[64];
    __shared__ int pairN[PAIR_CAP];
    __shared__ int pairK[PAIR_CAP];
    __shared__ int pcount;

    const int tid = threadIdx.x;
    const int w = tid >> 6, l = tid & 63;
    const int lg = l >> 4, lc = l & 15;
    const int nf = *count;

    c32s[tid] = C32[tid];
    c32s[tid + 256] = C32[tid + 256];
    c32s[tid + 512] = C32[tid + 512];
    c32s[tid + 768] = C32[tid + 768];

    for (int tile = blockIdx.x; tile * 64 < nf; tile += gridDim.x) {
        if (tid < 64) {
            int f = tile * 64 + tid; if (f >= nf) f = nf - 1;
            const int n = list[f];
            rowids[tid] = n;
            m1s[tid] = m1arr[n];
            packed[tid] = 0xFFFFFFFF00000000ULL | (unsigned)idx_arr[n];
        }
        if (tid == 0) pcount = 0;
        __syncthreads();

        const int slot = w * 16 + lc;
        const int myrow = rowids[slot];
        const float m1v = m1s[slot];

        // z B-frags direct from global (identical lane mapping to kdist_slice)
        f16x8 zhw[8];
        #pragma unroll
        for (int c = 0; c < 8; ++c) {
            const float* p = z + (size_t)myrow * DDIM + c * 32 + lg * 8;
            const float4 f0 = *reinterpret_cast<const float4*>(p);
            const float4 f1 = *reinterpret_cast<const float4*>(p + 4);
            float v[8] = {f0.x, f0.y, f0.z, f0.w, f1.x, f1.y, f1.z, f1.w};
            f16x8 H;
            #pragma unroll
            for (int q = 0; q < 8; ++q) H[q] = (_Float16)v[q];
            zhw[c] = H;
        }

        auto loadA = [&](int ct, f16x8* A) {
            #pragma unroll
            for (int c = 0; c < 8; ++c)
                A[c] = *reinterpret_cast<const f16x8*>(
                    cbfrag + (size_t)ct * 4096 + (c * 4 + lg) * 128 + lc * 8);
        };
        auto emitA = [&](const f16x8* A, int ct) {
            f32x4 acc = {0.f, 0.f, 0.f, 0.f};
            #pragma unroll
            for (int c = 0; c < 8; ++c)
                acc = __builtin_amdgcn_mfma_f32_16x16x32_f16(A[c], zhw[c], acc, 0, 0, 0);
            #pragma unroll
            for (int r = 0; r < 4; ++r) {
                const int code = ct * 16 + lg * 4 + r;
                const float s = fmaf(FOLDC, acc[r], c32s[code]);
                if (s <= m1v + MARGIN) {
                    const int p = atomicAdd(&pcount, 1);
                    if (p < PAIR_CAP) { pairN[p] = slot; pairK[p] = code; }
                }
            }
        };

        f16x8 A0[8], A1[8];
        loadA(0, A0);
        for (int ct = 0; ct < 64; ct += 2) {
            loadA(ct + 1, A1);
            emitA(A0, ct);
            loadA((ct + 2) & 63, A0);
            emitA(A1, ct + 1);
        }
        __syncthreads();

        // np-pairwise A per row
        #pragma unroll
        for (int it = 0; it < 4; ++it) {
            const int rs = (tid >> 4) + it * 16;
            const int l16 = tid & 15;
            const int half = l16 >> 3, j = l16 & 7;
            const float* p = z + (size_t)rowids[rs] * DDIM + half * 128 + j;
            float t0 = p[0];
            float rr = __fmul_rn(t0, t0);
            #pragma unroll
            for (int i = 1; i < 16; ++i) {
                const float t = p[i * 8];
                rr = __fadd_rn(rr, __fmul_rn(t, t));
            }
            float o = __fadd_rn(rr, __shfl_xor(rr, 1, 64));
            o = __fadd_rn(o, __shfl_xor(o, 2, 64));
            o = __fadd_rn(o, __shfl_xor(o, 4, 64));
            o = __fadd_rn(o, __shfl_xor(o, 8, 64));
            if (l16 == 0) arow[rs] = o;
        }
        __syncthreads();

        // refine: 16 lanes/pair, exact f64 dot -> dq on np f32 grid -> packed atomicMin
        const int npairs = min(pcount, PAIR_CAP);
        for (int p0 = 0; p0 < npairs; p0 += 16) {
            const int p = p0 + (tid >> 4);
            if (p < npairs) {
                const int rs = pairN[p], k = pairK[p];
                const int n = rowids[rs];
                const int l16 = tid & 15;
                const float* zp = z  + (size_t)n * DDIM + l16 * 16;
                const float* ep = cb + (size_t)k * DDIM + l16 * 16;
                double s = 0.0;
                #pragma unroll
                for (int t = 0; t < 16; t += 4) {
                    const float4 zv = *reinterpret_cast<const float4*>(zp + t);
                    const float4 ev = *reinterpret_cast<const float4*>(ep + t);
                    s = fma((double)ev.x, (double)zv.x, s);
                    s = fma((double)ev.y, (double)zv.y, s);
                    s = fma((double)ev.z, (double)zv.z, s);
                    s = fma((double)ev.w, (double)zv.w, s);
                }
                s += __shfl_xor(s, 1, 64);
                s += __shfl_xor(s, 2, 64);
                s += __shfl_xor(s, 4, 64);
                s += __shfl_xor(s, 8, 64);
                if (l16 == 0) {
                    const float Bf = (float)s;
                    const float t1 = __fsub_rn(arow[rs], __fmul_rn(2.0f, Bf));
                    const float dq = __fadd_rn(t1, c32s[k]);
                    const unsigned long long pk =
                        ((unsigned long long)__builtin_bit_cast(unsigned, dq) << 32) | (unsigned)k;
                    atomicMin(&packed[rs], pk);
                }
            }
        }
        __syncthreads();
        if (tid < 64 && tile * 64 + tid < nf)
            idx_arr[rowids[tid]] = (int)(packed[tid] & 0xFFFFFFFFu);
        __syncthreads();
    }
}

// ---------------- outputs ----------------
__global__ void kout(const float* __restrict__ z, const float* __restrict__ cb,
                     const int* __restrict__ idx_arr, float* __restrict__ out,
                     double* __restrict__ partials) {
    const int tid = threadIdx.x;
    const long long gid = (long long)blockIdx.x * 256 + tid;
    const long long stride = (long long)gridDim.x * 256;
    const long long tot4 = (long long)N_ROWS * DDIM / 4;
    double lsum = 0.0;
    for (long long i4 = gid; i4 < tot4; i4 += stride) {
        const int n  = (int)(i4 >> 6);
        const int d4 = (int)(i4 & 63) * 4;
        const int k  = idx_arr[n];
        const float4 e  = *reinterpret_cast<const float4*>(cb + (size_t)k * DDIM + d4);
        const float4 zz = *reinterpret_cast<const float4*>(z + (size_t)n * DDIM + d4);
        const float sx = __fsub_rn(e.x, zz.x), sy = __fsub_rn(e.y, zz.y);
        const float sz2 = __fsub_rn(e.z, zz.z), sw = __fsub_rn(e.w, zz.w);
        float4 o;
        o.x = __fadd_rn(zz.x, sx); o.y = __fadd_rn(zz.y, sy);
        o.z = __fadd_rn(zz.z, sz2); o.w = __fadd_rn(zz.w, sw);
        *reinterpret_cast<float4*>(out + i4 * 4) = o;
        lsum += (double)sx * sx + (double)sy * sy + (double)sz2 * sz2 + (double)sw * sw;
    }
    for (long long n = gid; n < N_ROWS; n += stride)
        out[(long long)N_ROWS * DDIM + 1 + n] = (float)idx_arr[n];
    __shared__ double red[256];
    red[tid] = lsum; __syncthreads();
    for (int s = 128; s > 0; s >>= 1) { if (tid < s) red[tid] += red[tid + s]; __syncthreads(); }
    if (tid == 0) partials[blockIdx.x] = red[0];
}

__global__ void kfin(const double* __restrict__ partials, int nb, float* __restrict__ out) {
    __shared__ double red[256];
    double s = 0.0;
    for (int i = threadIdx.x; i < nb; i += 256) s += partials[i];
    red[threadIdx.x] = s; __syncthreads();
    for (int t = 128; t > 0; t >>= 1) { if (threadIdx.x < t) red[threadIdx.x] += red[threadIdx.x + t]; __syncthreads(); }
    if (threadIdx.x == 0)
        out[(long long)N_ROWS * DDIM] =
            (float)(red[0] * 1.25 / ((double)N_ROWS * DDIM));  // (1+beta)*mean
}

extern "C" void kernel_launch(void* const* d_in, const int* in_sizes, int n_in,
                              void* d_out, int out_size, void* d_ws, size_t ws_size,
                              hipStream_t stream) {
    const float* z  = (const float*)d_in[0];
    const float* cb = (const float*)d_in[1];
    float* out = (float*)d_out;
    char* ws = (char*)d_ws;
    float*  C32      = (float*)(ws + 0);
    float*  m1arr    = (float*)(ws + 4096);
    int*    idx_arr  = (int*)(ws + 266240);
    int*    list     = (int*)(ws + 528384);
    int*    count    = (int*)(ws + 790528);
    double* partials = (double*)(ws + 790536);
    _Float16* cbfrag = (_Float16*)(ws + 807936);
    float4* part = (float4*)d_out;   // 4 MB scratch inside quantized region (kout overwrites)

    hipMemsetAsync(count, 0, 4, stream);
    krownorm<<<KCODES / 16, 256, 0, stream>>>(cb, C32);
    kprep<<<128, 256, 0, stream>>>(cb, cbfrag);
    hipFuncSetAttribute(reinterpret_cast<const void*>(&kdist_slice),
                        hipFuncAttributeMaxDynamicSharedMemorySize, 132096);
    kdist_slice<<<256, 512, 132096, stream>>>(z, cbfrag, C32, part);
    kmerge<<<N_ROWS / 256, 256, 0, stream>>>(part, idx_arr, m1arr, list, count);
    kcand<<<256, 256, 0, stream>>>(z, cb, cbfrag, C32, m1arr,
                                   list, count, idx_arr);
    kout<<<2048, 256, 0, stream>>>(z, cb, idx_arr, out, partials);
    kfin<<<1, 256, 0, stream>>>(partials, 2048, out);
}

// Round 9
// 145.292 us; speedup vs baseline: 5.2472x; 5.2472x over previous
//
#include <hip/hip_runtime.h>
#include <math.h>

#define N_ROWS 65536
#define DDIM   256
#define KCODES 1024
#define MARGIN 2.2e-4f    // >= 1.22e-4 (np f32-grid) + 2*4.4e-5 (C-S worst-case s~ err)
#define PAIR_CAP 2048
#define ESCALE 32768.0f   // 2^15: keeps f16 codebook out of subnormals
#define FOLDC  (-6.103515625e-05f)   // -2 * 2^-15 exact

typedef __attribute__((ext_vector_type(8))) _Float16 f16x8;  // 4 VGPR
typedef __attribute__((ext_vector_type(4))) float f32x4;

// ws layout (bytes):
//      0 : C32[1024]   f32  (np-pairwise codebook norms)
//   4096 : m1arr[65536] f32
// 266240 : idx_arr[65536] i32
// 528384 : list[65536]    i32
// 790528 : count i32 (+4 pad)
// 790536 : partials[2048] f64
// 807936 : cbfrag[512 KB] f16 codebook*2^15 in MFMA A-frag order

// ---------- numpy-pairwise f32 row-norm emulation (n=256), codebook only ----------
__global__ void krownorm(const float* __restrict__ x, float* __restrict__ out) {
    const int row = blockIdx.x * 16 + (threadIdx.x >> 4);
    const int l16 = threadIdx.x & 15;
    const int half = l16 >> 3, j = l16 & 7;
    const float* p = x + (size_t)row * DDIM + half * 128 + j;
    float t0 = p[0];
    float r = __fmul_rn(t0, t0);
    #pragma unroll
    for (int i = 1; i < 16; ++i) {
        const float t = p[i * 8];
        r = __fadd_rn(r, __fmul_rn(t, t));
    }
    float o = __fadd_rn(r, __shfl_xor(r, 1, 64));
    o = __fadd_rn(o, __shfl_xor(o, 2, 64));
    o = __fadd_rn(o, __shfl_xor(o, 4, 64));
    o = __fadd_rn(o, __shfl_xor(o, 8, 64));
    if (l16 == 0) out[row] = o;
}

// ---------- codebook*2^15 -> f16 A-fragments ----------
// elem j of (ct,c,g,code): cbfrag[ct*4096 + (c*4+g)*128 + code*8 + j]
__global__ void kprep(const float* __restrict__ cb, _Float16* __restrict__ frag) {
    const int u = blockIdx.x * 256 + threadIdx.x;     // 32768 units
    const int code = u & 15, g = (u >> 4) & 3, c = (u >> 6) & 7, ct = u >> 9;
    const float* src = cb + (size_t)(ct * 16 + code) * DDIM + c * 32 + g * 8;
    const float4 f0 = *reinterpret_cast<const float4*>(src);
    const float4 f1 = *reinterpret_cast<const float4*>(src + 4);
    float v[8] = {f0.x, f0.y, f0.z, f0.w, f1.x, f1.y, f1.z, f1.w};
    f16x8 H;
    #pragma unroll
    for (int j = 0; j < 8; ++j) H[j] = (_Float16)(v[j] * ESCALE);
    *reinterpret_cast<f16x8*>(frag + (size_t)ct * 4096 + (c * 4 + g) * 128 + code * 8) = H;
}

// ---- phase A: LDS double-buffered f16 MFMA, reg-prefetch 2 tiles ahead ----
// 256 thr = 4 waves, wave w owns rows blk*128 + w*32 .. +32 (two 16-row tiles in regs).
// Per ct: 8 ds_read_b128 + 16 MFMA + sort-network fold. Staging: r0/r1 hold tile
// ct+2 (loop-carried regs -> compiler cannot sink the load), ds_write between
// two barriers (WAR-clean).
__global__ __launch_bounds__(256, 2) void kdist(const float* __restrict__ z,
        const uint4* __restrict__ cb4, const float* __restrict__ C32,
        int* __restrict__ idx_arr, float* __restrict__ m1arr,
        int* __restrict__ list, int* __restrict__ count) {
    __shared__ __align__(16) _Float16 cbb[2][4096];   // 16 KB double buffer
    __shared__ float c32s[1024];                      // 4 KB

    const int tid = threadIdx.x;
    const int w = tid >> 6, l = tid & 63;
    const int lg = l >> 4, lc = l & 15;
    const int rbase = blockIdx.x * 128 + w * 32;

    // issue tile-0 codebook loads first
    uint4 r0 = cb4[tid], r1 = cb4[tid + 256];

    // z B-frags direct from global (identical mapping to kcand)
    f16x8 zh[2][8];
    #pragma unroll
    for (int t = 0; t < 2; ++t) {
        const int row = rbase + t * 16 + lc;
        #pragma unroll
        for (int c = 0; c < 8; ++c) {
            const float* p = z + (size_t)row * DDIM + c * 32 + lg * 8;
            const float4 f0 = *reinterpret_cast<const float4*>(p);
            const float4 f1 = *reinterpret_cast<const float4*>(p + 4);
            float v[8] = {f0.x, f0.y, f0.z, f0.w, f1.x, f1.y, f1.z, f1.w};
            f16x8 H;
            #pragma unroll
            for (int q = 0; q < 8; ++q) H[q] = (_Float16)v[q];
            zh[t][c] = H;
        }
    }

    c32s[tid] = C32[tid];
    c32s[tid + 256] = C32[tid + 256];
    c32s[tid + 512] = C32[tid + 512];
    c32s[tid + 768] = C32[tid + 768];
    {   // tile 0 -> buffer 0; then start tile-1 loads
        uint4* d = reinterpret_cast<uint4*>(&cbb[0][0]);
        d[tid] = r0; d[tid + 256] = r1;
    }
    r0 = cb4[512 + tid]; r1 = cb4[512 + tid + 256];
    __syncthreads();

    float m1a = __builtin_inff(), m2a = __builtin_inff(); int i1a = 0;
    float m1b = __builtin_inff(), m2b = __builtin_inff(); int i1b = 0;

    for (int ct = 0; ct < 64; ++ct) {
        const _Float16* buf = cbb[ct & 1];
        f32x4 acc0 = {0.f, 0.f, 0.f, 0.f}, acc1 = {0.f, 0.f, 0.f, 0.f};
        #pragma unroll
        for (int c = 0; c < 8; ++c) {
            const f16x8 A = *reinterpret_cast<const f16x8*>(
                &buf[(c * 4 + lg) * 128 + lc * 8]);
            acc0 = __builtin_amdgcn_mfma_f32_16x16x32_f16(A, zh[0][c], acc0, 0, 0, 0);
            acc1 = __builtin_amdgcn_mfma_f32_16x16x32_f16(A, zh[1][c], acc1, 0, 0, 0);
        }
        const float4 Cc = *reinterpret_cast<const float4*>(&c32s[ct * 16 + lg * 4]);
        const int base = ct * 16 + lg * 4;
        {   // track a (same score expression as kcand -> bitwise identical)
            const float s0 = fmaf(FOLDC, acc0[0], Cc.x);
            const float s1 = fmaf(FOLDC, acc0[1], Cc.y);
            const float s2 = fmaf(FOLDC, acc0[2], Cc.z);
            const float s3 = fmaf(FOLDC, acc0[3], Cc.w);
            const float lo01 = fminf(s0, s1), hi01 = fmaxf(s0, s1);
            const float lo23 = fminf(s2, s3), hi23 = fmaxf(s2, s3);
            const float a1 = fminf(lo01, lo23);
            const float a2 = fminf(fmaxf(lo01, lo23), fminf(hi01, hi23));
            const int it = (s0 == a1) ? base : (s1 == a1) ? base + 1
                         : (s2 == a1) ? base + 2 : base + 3;
            if (a1 < m1a) { m2a = fminf(m1a, a2); m1a = a1; i1a = it; }
            else          { m2a = fminf(m2a, a1); }    // tie -> m2==m1 -> flagged
        }
        {   // track b
            const float s0 = fmaf(FOLDC, acc1[0], Cc.x);
            const float s1 = fmaf(FOLDC, acc1[1], Cc.y);
            const float s2 = fmaf(FOLDC, acc1[2], Cc.z);
            const float s3 = fmaf(FOLDC, acc1[3], Cc.w);
            const float lo01 = fminf(s0, s1), hi01 = fmaxf(s0, s1);
            const float lo23 = fminf(s2, s3), hi23 = fmaxf(s2, s3);
            const float a1 = fminf(lo01, lo23);
            const float a2 = fminf(fmaxf(lo01, lo23), fminf(hi01, hi23));
            const int it = (s0 == a1) ? base : (s1 == a1) ? base + 1
                         : (s2 == a1) ? base + 2 : base + 3;
            if (a1 < m1b) { m2b = fminf(m1b, a2); m1b = a1; i1b = it; }
            else          { m2b = fminf(m2b, a1); }
        }
        __syncthreads();                       // bar1: all waves done reading buf[ct&1]
        if (ct < 63) {
            uint4* d = reinterpret_cast<uint4*>(&cbb[(ct + 1) & 1][0]);
            d[tid] = r0; d[tid + 256] = r1;    // write tile ct+1 (loaded ~1.2 iters ago)
            if (ct < 62) {
                r0 = cb4[(size_t)(ct + 2) * 512 + tid];
                r1 = cb4[(size_t)(ct + 2) * 512 + tid + 256];
            }
            __syncthreads();                   // bar2: tile ct+1 visible to all
        }
    }

    // merge the 4 lane-groups (lanes l, l^16, l^32, l^48 share a z-row)
    #pragma unroll
    for (int off = 16; off < 64; off <<= 1) {
        float om1 = __shfl_xor(m1a, off, 64);
        float om2 = __shfl_xor(m2a, off, 64);
        int   oi  = __shfl_xor(i1a, off, 64);
        if (om1 < m1a) { m2a = fminf(m1a, om2); m1a = om1; i1a = oi; }
        else { m2a = fminf(m2a, om1); if (om1 == m1a) i1a = min(i1a, oi); }
        om1 = __shfl_xor(m1b, off, 64);
        om2 = __shfl_xor(m2b, off, 64);
        oi  = __shfl_xor(i1b, off, 64);
        if (om1 < m1b) { m2b = fminf(m1b, om2); m1b = om1; i1b = oi; }
        else { m2b = fminf(m2b, om1); if (om1 == m1b) i1b = min(i1b, oi); }
    }
    if (lg == 0) {
        const int na = rbase + lc;
        idx_arr[na] = i1a; m1arr[na] = m1a;
        if (m2a - m1a < MARGIN) { const int p = atomicAdd(count, 1); list[p] = na; }
        const int nb = na + 16;
        idx_arr[nb] = i1b; m1arr[nb] = m1b;
        if (m2b - m1b < MARGIN) { const int p = atomicAdd(count, 1); list[p] = nb; }
    }
}

// -------- phase B: batched candidate emission (bitwise-identical s~) + exact refine --------
__global__ __launch_bounds__(256, 4) void kcand(const float* __restrict__ z,
        const float* __restrict__ cb, const _Float16* __restrict__ cbfrag,
        const float* __restrict__ C32, const float* __restrict__ m1arr,
        const int* __restrict__ list, const int* __restrict__ count,
        int* __restrict__ idx_arr) {
    __shared__ float c32s[1024];
    __shared__ int rowids[64];
    __shared__ float m1s[64];
    __shared__ float arow[64];
    __shared__ unsigned long long packed[64];
    __shared__ int pairN[PAIR_CAP];
    __shared__ int pairK[PAIR_CAP];
    __shared__ int pcount;

    const int tid = threadIdx.x;
    const int w = tid >> 6, l = tid & 63;
    const int lg = l >> 4, lc = l & 15;
    const int nf = *count;

    c32s[tid] = C32[tid];
    c32s[tid + 256] = C32[tid + 256];
    c32s[tid + 512] = C32[tid + 512];
    c32s[tid + 768] = C32[tid + 768];

    for (int tile = blockIdx.x; tile * 64 < nf; tile += gridDim.x) {
        if (tid < 64) {
            int f = tile * 64 + tid; if (f >= nf) f = nf - 1;
            const int n = list[f];
            rowids[tid] = n;
            m1s[tid] = m1arr[n];
            packed[tid] = 0xFFFFFFFF00000000ULL | (unsigned)idx_arr[n];
        }
        if (tid == 0) pcount = 0;
        __syncthreads();

        const int slot = w * 16 + lc;
        const int myrow = rowids[slot];
        const float m1v = m1s[slot];

        // z B-frags direct from global (identical lane mapping to kdist)
        f16x8 zhw[8];
        #pragma unroll
        for (int c = 0; c < 8; ++c) {
            const float* p = z + (size_t)myrow * DDIM + c * 32 + lg * 8;
            const float4 f0 = *reinterpret_cast<const float4*>(p);
            const float4 f1 = *reinterpret_cast<const float4*>(p + 4);
            float v[8] = {f0.x, f0.y, f0.z, f0.w, f1.x, f1.y, f1.z, f1.w};
            f16x8 H;
            #pragma unroll
            for (int q = 0; q < 8; ++q) H[q] = (_Float16)v[q];
            zhw[c] = H;
        }

        auto loadA = [&](int ct, f16x8* A) {
            #pragma unroll
            for (int c = 0; c < 8; ++c)
                A[c] = *reinterpret_cast<const f16x8*>(
                    cbfrag + (size_t)ct * 4096 + (c * 4 + lg) * 128 + lc * 8);
        };
        auto emitA = [&](const f16x8* A, int ct) {
            f32x4 acc = {0.f, 0.f, 0.f, 0.f};
            #pragma unroll
            for (int c = 0; c < 8; ++c)
                acc = __builtin_amdgcn_mfma_f32_16x16x32_f16(A[c], zhw[c], acc, 0, 0, 0);
            #pragma unroll
            for (int r = 0; r < 4; ++r) {
                const int code = ct * 16 + lg * 4 + r;
                const float s = fmaf(FOLDC, acc[r], c32s[code]);
                if (s <= m1v + MARGIN) {
                    const int p = atomicAdd(&pcount, 1);
                    if (p < PAIR_CAP) { pairN[p] = slot; pairK[p] = code; }
                }
            }
        };

        f16x8 A0[8], A1[8];
        loadA(0, A0);
        for (int ct = 0; ct < 64; ct += 2) {
            loadA(ct + 1, A1);
            emitA(A0, ct);
            loadA((ct + 2) & 63, A0);
            emitA(A1, ct + 1);
        }
        __syncthreads();

        // np-pairwise A per row
        #pragma unroll
        for (int it = 0; it < 4; ++it) {
            const int rs = (tid >> 4) + it * 16;
            const int l16 = tid & 15;
            const int half = l16 >> 3, j = l16 & 7;
            const float* p = z + (size_t)rowids[rs] * DDIM + half * 128 + j;
            float t0 = p[0];
            float rr = __fmul_rn(t0, t0);
            #pragma unroll
            for (int i = 1; i < 16; ++i) {
                const float t = p[i * 8];
                rr = __fadd_rn(rr, __fmul_rn(t, t));
            }
            float o = __fadd_rn(rr, __shfl_xor(rr, 1, 64));
            o = __fadd_rn(o, __shfl_xor(o, 2, 64));
            o = __fadd_rn(o, __shfl_xor(o, 4, 64));
            o = __fadd_rn(o, __shfl_xor(o, 8, 64));
            if (l16 == 0) arow[rs] = o;
        }
        __syncthreads();

        // refine: 16 lanes/pair, exact f64 dot -> dq on np f32 grid -> packed atomicMin
        const int npairs = min(pcount, PAIR_CAP);
        for (int p0 = 0; p0 < npairs; p0 += 16) {
            const int p = p0 + (tid >> 4);
            if (p < npairs) {
                const int rs = pairN[p], k = pairK[p];
                const int n = rowids[rs];
                const int l16 = tid & 15;
                const float* zp = z  + (size_t)n * DDIM + l16 * 16;
                const float* ep = cb + (size_t)k * DDIM + l16 * 16;
                double s = 0.0;
                #pragma unroll
                for (int t = 0; t < 16; t += 4) {
                    const float4 zv = *reinterpret_cast<const float4*>(zp + t);
                    const float4 ev = *reinterpret_cast<const float4*>(ep + t);
                    s = fma((double)ev.x, (double)zv.x, s);
                    s = fma((double)ev.y, (double)zv.y, s);
                    s = fma((double)ev.z, (double)zv.z, s);
                    s = fma((double)ev.w, (double)zv.w, s);
                }
                s += __shfl_xor(s, 1, 64);
                s += __shfl_xor(s, 2, 64);
                s += __shfl_xor(s, 4, 64);
                s += __shfl_xor(s, 8, 64);
                if (l16 == 0) {
                    const float Bf = (float)s;
                    const float t1 = __fsub_rn(arow[rs], __fmul_rn(2.0f, Bf));
                    const float dq = __fadd_rn(t1, c32s[k]);
                    const unsigned long long pk =
                        ((unsigned long long)__builtin_bit_cast(unsigned, dq) << 32) | (unsigned)k;
                    atomicMin(&packed[rs], pk);
                }
            }
        }
        __syncthreads();
        if (tid < 64 && tile * 64 + tid < nf)
            idx_arr[rowids[tid]] = (int)(packed[tid] & 0xFFFFFFFFu);
        __syncthreads();
    }
}

// ---------------- outputs ----------------
__global__ void kout(const float* __restrict__ z, const float* __restrict__ cb,
                     const int* __restrict__ idx_arr, float* __restrict__ out,
                     double* __restrict__ partials) {
    const int tid = threadIdx.x;
    const long long gid = (long long)blockIdx.x * 256 + tid;
    const long long stride = (long long)gridDim.x * 256;
    const long long tot4 = (long long)N_ROWS * DDIM / 4;
    double lsum = 0.0;
    for (long long i4 = gid; i4 < tot4; i4 += stride) {
        const int n  = (int)(i4 >> 6);
        const int d4 = (int)(i4 & 63) * 4;
        const int k  = idx_arr[n];
        const float4 e  = *reinterpret_cast<const float4*>(cb + (size_t)k * DDIM + d4);
        const float4 zz = *reinterpret_cast<const float4*>(z + (size_t)n * DDIM + d4);
        const float sx = __fsub_rn(e.x, zz.x), sy = __fsub_rn(e.y, zz.y);
        const float sz2 = __fsub_rn(e.z, zz.z), sw = __fsub_rn(e.w, zz.w);
        float4 o;
        o.x = __fadd_rn(zz.x, sx); o.y = __fadd_rn(zz.y, sy);
        o.z = __fadd_rn(zz.z, sz2); o.w = __fadd_rn(zz.w, sw);
        *reinterpret_cast<float4*>(out + i4 * 4) = o;
        lsum += (double)sx * sx + (double)sy * sy + (double)sz2 * sz2 + (double)sw * sw;
    }
    for (long long n = gid; n < N_ROWS; n += stride)
        out[(long long)N_ROWS * DDIM + 1 + n] = (float)idx_arr[n];
    __shared__ double red[256];
    red[tid] = lsum; __syncthreads();
    for (int s = 128; s > 0; s >>= 1) { if (tid < s) red[tid] += red[tid + s]; __syncthreads(); }
    if (tid == 0) partials[blockIdx.x] = red[0];
}

__global__ void kfin(const double* __restrict__ partials, int nb, float* __restrict__ out) {
    __shared__ double red[256];
    double s = 0.0;
    for (int i = threadIdx.x; i < nb; i += 256) s += partials[i];
    red[threadIdx.x] = s; __syncthreads();
    for (int t = 128; t > 0; t >>= 1) { if (threadIdx.x < t) red[threadIdx.x] += red[threadIdx.x + t]; __syncthreads(); }
    if (threadIdx.x == 0)
        out[(long long)N_ROWS * DDIM] =
            (float)(red[0] * 1.25 / ((double)N_ROWS * DDIM));  // (1+beta)*mean
}

extern "C" void kernel_launch(void* const* d_in, const int* in_sizes, int n_in,
                              void* d_out, int out_size, void* d_ws, size_t ws_size,
                              hipStream_t stream) {
    const float* z  = (const float*)d_in[0];
    const float* cb = (const float*)d_in[1];
    float* out = (float*)d_out;
    char* ws = (char*)d_ws;
    float*  C32      = (float*)(ws + 0);
    float*  m1arr    = (float*)(ws + 4096);
    int*    idx_arr  = (int*)(ws + 266240);
    int*    list     = (int*)(ws + 528384);
    int*    count    = (int*)(ws + 790528);
    double* partials = (double*)(ws + 790536);
    _Float16* cbfrag = (_Float16*)(ws + 807936);

    hipMemsetAsync(count, 0, 4, stream);
    krownorm<<<KCODES / 16, 256, 0, stream>>>(cb, C32);
    kprep<<<128, 256, 0, stream>>>(cb, cbfrag);
    kdist<<<N_ROWS / 128, 256, 0, stream>>>(z, (const uint4*)cbfrag, C32,
                                            idx_arr, m1arr, list, count);
    kcand<<<256, 256, 0, stream>>>(z, cb, cbfrag, C32, m1arr,
                                   list, count, idx_arr);
    kout<<<2048, 256, 0, stream>>>(z, cb, idx_arr, out, partials);
    kfin<<<1, 256, 0, stream>>>(partials, 2048, out);
}